// Round 3
// baseline (441.001 us; speedup 1.0000x reference)
//
#include <hip/hip_runtime.h>
#include <hip/hip_bf16.h>
#include <math.h>

// BezierDeformableAttention on MI355X (gfx950).
// Shapes: B=4 N=900 D=256 C=256 H=W=200, HEADS=8 PTS=4 K=10, hd=32.
// I/O dtype: float32 (per reference). Internals: bf16 MFMA, f32 accumulate.
//
// Pipeline (9 dispatches):
//  1. prep_weights:  f32 W* -> bf16 transposed (WqT/WvT/[Woff|Wattn]T/WmoT/WoT) + boa
//  2. convert_q:     query f32 -> bf16
//  3. transpose_bev: (B,C,HW) f32 -> bevT (B,HW,C) bf16   [246 MB HBM]
//  4. gemm q:        q = query @ Wq + bq    -> q_bf16 + q_f32 (residual)
//  5. gemm offattn:  [off|attn] = q @ [Woff|Wattn] + bias -> f32 (3600x96)
//  6. gemm vT:       v^T = WvT(256x256) . bevT -> v[b][h][pix][32] bf16  [21 GF MFMA]
//  7. sampler:       bezier + softmax + bilinear gather + head reduce -> bf16
//  8. gemm out1:     attn_out @ Wmo + bmo + q  (residual) -> bf16
//  9. gemm out2:     out1 @ Wo + bo -> d_out (f32)

typedef unsigned short u16;
typedef unsigned int u32;
typedef short bf16x8 __attribute__((ext_vector_type(8)));
typedef float f32x4 __attribute__((ext_vector_type(4)));

__device__ __forceinline__ float bf2f(u16 u) {
  union { u32 i; float f; } c; c.i = ((u32)u) << 16; return c.f;
}
__device__ __forceinline__ u16 f2bf(float f) {  // RNE
  union { float f; u32 i; } c; c.f = f;
  u32 u = c.i;
  return (u16)((u + 0x7FFFu + ((u >> 16) & 1u)) >> 16);
}
__device__ __forceinline__ int imin(int a, int b) { return a < b ? a : b; }
__device__ __forceinline__ int imax(int a, int b) { return a > b ? a : b; }

// ---------------------------------------------------------------- weights prep
// All weight matrices f32 in, bf16 transposed out. boa = concat(boff,battn) f32.
__global__ __launch_bounds__(256) void prep_weights(
    const float* __restrict__ Wq, const float* __restrict__ Wv,
    const float* __restrict__ Woff, const float* __restrict__ Wattn,
    const float* __restrict__ Wmo, const float* __restrict__ Wo,
    const float* __restrict__ boff, const float* __restrict__ battn,
    u16* __restrict__ wqT, u16* __restrict__ wvT, u16* __restrict__ woaT,
    u16* __restrict__ wmoT, u16* __restrict__ woT, float* __restrict__ boa)
{
  int idx = blockIdx.x * 256 + threadIdx.x;  // 256 blocks -> 65536 threads
  if (idx < 65536) {
    int r = idx >> 8, c = idx & 255;  // out[r][c] = in[c][r]
    wqT[idx]  = f2bf(Wq[c * 256 + r]);
    wvT[idx]  = f2bf(Wv[c * 256 + r]);
    wmoT[idx] = f2bf(Wmo[c * 256 + r]);
    woT[idx]  = f2bf(Wo[c * 256 + r]);
  }
  if (idx < 96 * 256) {
    int n = idx >> 8, k = idx & 255;
    woaT[idx] = f2bf((n < 64) ? Woff[k * 64 + n] : Wattn[k * 32 + (n - 64)]);
  }
  if (idx < 96) boa[idx] = (idx < 64) ? boff[idx] : battn[idx - 64];
}

// ---------------------------------------------------------------- f32 -> bf16
__global__ __launch_bounds__(256) void convert_q(
    const float* __restrict__ in, u16* __restrict__ out)  // 921600 elems
{
  int i = (blockIdx.x * 256 + threadIdx.x) * 4;
  float4 v = *(const float4*)(in + i);
  uint2 st;
  st.x = (u32)f2bf(v.x) | ((u32)f2bf(v.y) << 16);
  st.y = (u32)f2bf(v.z) | ((u32)f2bf(v.w) << 16);
  *(uint2*)(out + i) = st;
}

// ---------------------------------------------------------------- bev transpose
// (B,256,40000) f32 -> (B,40000,256) bf16. 64x64 tiles. LDS stride 68 (8B-aligned
// uint2 stores for odd rows; banks distinct in both phases).
__global__ __launch_bounds__(256) void transpose_bev(
    const float* __restrict__ bev, u16* __restrict__ bevT)
{
  __shared__ __align__(16) u16 t[64 * 68];
  const int b = blockIdx.z, c0 = blockIdx.y * 64, p0 = blockIdx.x * 64;
  const float* src = bev + ((size_t)b * 256 + c0) * 40000 + p0;
#pragma unroll
  for (int it = 0; it < 4; ++it) {
    int slot = it * 256 + threadIdx.x;        // 0..1023
    int r = slot >> 4, i = slot & 15;         // c-row r, pix-group i (4 f32)
    float4 dv = *(const float4*)(src + (size_t)r * 40000 + i * 4);
    uint2 st;
    st.x = (u32)f2bf(dv.x) | ((u32)f2bf(dv.y) << 16);
    st.y = (u32)f2bf(dv.z) | ((u32)f2bf(dv.w) << 16);
    *(uint2*)&t[r * 68 + i * 4] = st;
  }
  __syncthreads();
  u16* ob = bevT + ((size_t)b * 40000 + p0) * 256 + c0;
#pragma unroll
  for (int it = 0; it < 2; ++it) {
    int slot = it * 256 + threadIdx.x;        // 0..511
    int pr = slot >> 3, ci = slot & 7;        // pix-row pr, c-group ci (8 bf16)
    u32 w0 = (u32)t[(ci * 8 + 0) * 68 + pr] | ((u32)t[(ci * 8 + 1) * 68 + pr] << 16);
    u32 w1 = (u32)t[(ci * 8 + 2) * 68 + pr] | ((u32)t[(ci * 8 + 3) * 68 + pr] << 16);
    u32 w2 = (u32)t[(ci * 8 + 4) * 68 + pr] | ((u32)t[(ci * 8 + 5) * 68 + pr] << 16);
    u32 w3 = (u32)t[(ci * 8 + 6) * 68 + pr] | ((u32)t[(ci * 8 + 7) * 68 + pr] << 16);
    uint4 ov; ov.x = w0; ov.y = w1; ov.z = w2; ov.w = w3;
    *(uint4*)(ob + (size_t)pr * 256 + ci * 8) = ov;
  }
}

// ---------------------------------------------------------------- MFMA GEMM
// C[M,N] = A[M,K] * Bt[N,K]^T (+bias f32)(+res f32). 128x128 tile, BK=32,
// 4 waves, each 64x64 = 4x4 MFMA 16x16x32. K multiple of 32 (256 here).
enum { GM_F32 = 0, GM_BF16 = 1, GM_BOTH = 2, GM_V = 3 };
// GM_V: rows = d (M=256), cols = pix; bias[row]; store v[b][h][pix][32] bf16.

template <int MODE, bool HAS_RES>
__global__ __launch_bounds__(256) void gemm_bt(
    const u16* __restrict__ A, const u16* __restrict__ Bt,
    const float* __restrict__ bias, const float* __restrict__ res,
    u16* __restrict__ outb, float* __restrict__ outf,
    int M, int N, int K, long long btStrideZ, long long outStrideZ)
{
  __shared__ __align__(16) u16 lA[128 * 32];
  __shared__ __align__(16) u16 lB[128 * 32];
  const int tid = threadIdx.x;
  const int wv = tid >> 6, lane = tid & 63;
  const int m0 = blockIdx.y * 128, n0 = blockIdx.x * 128;
  const u16* Bz = Bt + (size_t)blockIdx.z * btStrideZ;

  // staging: wave stages chunks {wv, wv+4}; chunk = 16 rows x 32 k (1 KB).
  const int crow = lane >> 2;        // row within chunk
  const int ckoff = (lane & 3) * 8;  // k offset (8 bf16 = 16B)
  const int a1 = imin(m0 + wv * 16 + crow, M - 1);
  const int a2 = imin(m0 + (wv + 4) * 16 + crow, M - 1);
  const int b1 = imin(n0 + wv * 16 + crow, N - 1);
  const int b2 = imin(n0 + (wv + 4) * 16 + crow, N - 1);
  const u16* gA1 = A + (size_t)a1 * K + ckoff;
  const u16* gA2 = A + (size_t)a2 * K + ckoff;
  const u16* gB1 = Bz + (size_t)b1 * K + ckoff;
  const u16* gB2 = Bz + (size_t)b2 * K + ckoff;
  u16* lA1 = lA + wv * 512;  u16* lA2 = lA + (wv + 4) * 512;
  u16* lB1 = lB + wv * 512;  u16* lB2 = lB + (wv + 4) * 512;

  const int fm = (wv & 1) * 64, fn = (wv >> 1) * 64;
  const int fr = lane & 15, fk = (lane >> 4) * 8;

  f32x4 acc[4][4];
#pragma unroll
  for (int i = 0; i < 4; ++i)
#pragma unroll
    for (int j = 0; j < 4; ++j) acc[i][j] = (f32x4){0.f, 0.f, 0.f, 0.f};

  for (int k0 = 0; k0 < K; k0 += 32) {
    uint4 ra1 = *(const uint4*)(gA1 + k0);
    uint4 ra2 = *(const uint4*)(gA2 + k0);
    uint4 rb1 = *(const uint4*)(gB1 + k0);
    uint4 rb2 = *(const uint4*)(gB2 + k0);
    __syncthreads();  // prior iter's LDS reads done
    *(uint4*)(lA1 + lane * 8) = ra1;
    *(uint4*)(lA2 + lane * 8) = ra2;
    *(uint4*)(lB1 + lane * 8) = rb1;
    *(uint4*)(lB2 + lane * 8) = rb2;
    __syncthreads();
    bf16x8 af[4], bfv[4];
#pragma unroll
    for (int i = 0; i < 4; ++i)
      af[i] = *(const bf16x8*)&lA[(fm + i * 16 + fr) * 32 + fk];
#pragma unroll
    for (int j = 0; j < 4; ++j)
      bfv[j] = *(const bf16x8*)&lB[(fn + j * 16 + fr) * 32 + fk];
#pragma unroll
    for (int i = 0; i < 4; ++i)
#pragma unroll
      for (int j = 0; j < 4; ++j)
        acc[i][j] = __builtin_amdgcn_mfma_f32_16x16x32_bf16(af[i], bfv[j], acc[i][j], 0, 0, 0);
  }

  // epilogue: C/D layout col=lane&15, row=(lane>>4)*4+reg  [measured m89/m91]
  const int quad = lane >> 4;
#pragma unroll
  for (int j = 0; j < 4; ++j) {
    const int n = n0 + fn + j * 16 + fr;
    const bool nok = (n < N);
    float bcol = 0.f;
    if (MODE != GM_V) bcol = bias[nok ? n : 0];
#pragma unroll
    for (int i = 0; i < 4; ++i) {
      const int mb = m0 + fm + i * 16 + quad * 4;  // 4-aligned
      if (MODE == GM_V) {
        if (nok) {
          u16 u0 = f2bf(acc[i][j][0] + bias[mb + 0]);
          u16 u1 = f2bf(acc[i][j][1] + bias[mb + 1]);
          u16 u2 = f2bf(acc[i][j][2] + bias[mb + 2]);
          u16 u3 = f2bf(acc[i][j][3] + bias[mb + 3]);
          size_t off = (size_t)blockIdx.z * outStrideZ +
                       (size_t)(mb >> 5) * (40000 * 32) + (size_t)n * 32 + (mb & 31);
          uint2 st; st.x = (u32)u0 | ((u32)u1 << 16); st.y = (u32)u2 | ((u32)u3 << 16);
          *(uint2*)(outb + off) = st;
        }
      } else {
#pragma unroll
        for (int r = 0; r < 4; ++r) {
          const int m = mb + r;
          if (m < M && nok) {
            float x = acc[i][j][r] + bcol;
            if (HAS_RES) x += res[(size_t)m * N + n];
            if (MODE == GM_F32) outf[(size_t)m * N + n] = x;
            else if (MODE == GM_BF16) outb[(size_t)m * N + n] = f2bf(x);
            else { outb[(size_t)m * N + n] = f2bf(x); outf[(size_t)m * N + n] = x; }
          }
        }
      }
    }
  }
}

// ---------------------------------------------------------------- sampler
// One wave per (b,n,h): lanes = 2 sample-halves x 32 channels.
__global__ __launch_bounds__(256) void sampler(
    const float* __restrict__ ctrl,  // (3600,4,2) f32
    const float* __restrict__ pc,    // (6,) f32
    const float* __restrict__ oa_,   // (3600,96) f32: [0:64) off, [64:96) attn
    const u16* __restrict__ v,       // (B,8,40000,32) bf16
    u16* __restrict__ attn_out)      // (3600,256) bf16
{
  __shared__ int   sX0[4][40], sY0[4][40];
  __shared__ float sWx[4][40], sWy[4][40], sAw[4][40];
  const int w = threadIdx.x >> 6, lane = threadIdx.x & 63;
  const int wid = blockIdx.x * 4 + w;     // (b*8+h)*900 + n
  const int n = wid % 900, bh = wid / 900;
  const int h = bh & 7, b = bh >> 3;
  const int row = b * 900 + n;

  if (lane < 40) {
    const int k = lane >> 2, p = lane & 3;
    const float t = (float)k * (1.0f / 9.0f), u = 1.f - t;
    const float c0 = u * u * u, c1 = 3.f * u * u * t, c2 = 3.f * u * t * t, c3 = t * t * t;
    const float* cp = ctrl + (size_t)row * 8;
    float cx = c0 * cp[0] + c1 * cp[2] + c2 * cp[4] + c3 * cp[6];
    float cy = c0 * cp[1] + c1 * cp[3] + c2 * cp[5] + c3 * cp[7];
    float nx = (cx - pc[0]) / (pc[3] - pc[0]);
    float ny = (cy - pc[1]) / (pc[4] - pc[1]);
    nx = fminf(fmaxf(nx, 0.01f), 0.99f);
    ny = fminf(fmaxf(ny, 0.01f), 0.99f);
    const float* oa = oa_ + (size_t)row * 96;
    float ox = oa[h * 8 + p * 2 + 0], oy = oa[h * 8 + p * 2 + 1];
    float l0 = oa[64 + h * 4 + 0], l1 = oa[64 + h * 4 + 1];
    float l2 = oa[64 + h * 4 + 2], l3 = oa[64 + h * 4 + 3];
    float mx = fmaxf(fmaxf(l0, l1), fmaxf(l2, l3));
    float e0 = __expf(l0 - mx), e1 = __expf(l1 - mx), e2 = __expf(l2 - mx), e3 = __expf(l3 - mx);
    float lp = (p == 0) ? l0 : (p == 1) ? l1 : (p == 2) ? l2 : l3;
    float aw = __expf(lp - mx) / (e0 + e1 + e2 + e3);
    float gx = (nx + ox * (1.f / 200.f)) * 200.f - 0.5f;
    float gy = (ny + oy * (1.f / 200.f)) * 200.f - 0.5f;
    float x0 = floorf(gx), y0 = floorf(gy);
    sX0[w][lane] = (int)x0; sY0[w][lane] = (int)y0;
    sWx[w][lane] = gx - x0; sWy[w][lane] = gy - y0; sAw[w][lane] = aw;
  }
  __syncthreads();

  const int sub = lane >> 5, ch = lane & 31;
  const u16* vb = v + ((size_t)(b * 8 + h)) * (40000 * 32) + ch;
  float acc = 0.f;
#pragma unroll 4
  for (int i = 0; i < 20; ++i) {
    const int s = sub * 20 + i;
    const int x0 = sX0[w][s], y0 = sY0[w][s];
    const float wx = sWx[w][s], wy = sWy[w][s], aw = sAw[w][s];
    const int x1 = x0 + 1, y1 = y0 + 1;
    const int cx0 = imin(imax(x0, 0), 199), cx1 = imin(imax(x1, 0), 199);
    const int cy0 = imin(imax(y0, 0), 199), cy1 = imin(imax(y1, 0), 199);
    const bool vx0 = (u32)x0 < 200u, vx1 = (u32)x1 < 200u;
    const bool vy0 = (u32)y0 < 200u, vy1 = (u32)y1 < 200u;
    const u16* r0 = vb + (size_t)(cy0 * 200) * 32;
    const u16* r1 = vb + (size_t)(cy1 * 200) * 32;
    float f00 = bf2f(r0[cx0 * 32]);
    float f10 = bf2f(r0[cx1 * 32]);
    float f01 = bf2f(r1[cx0 * 32]);
    float f11 = bf2f(r1[cx1 * 32]);
    float w00 = (vx0 && vy0) ? (1.f - wx) * (1.f - wy) : 0.f;
    float w10 = (vx1 && vy0) ? wx * (1.f - wy) : 0.f;
    float w01 = (vx0 && vy1) ? (1.f - wx) * wy : 0.f;
    float w11 = (vx1 && vy1) ? wx * wy : 0.f;
    acc += aw * (w00 * f00 + w10 * f10 + w01 * f01 + w11 * f11);
  }
  acc += __shfl_down(acc, 32);
  if (lane < 32) attn_out[(size_t)row * 256 + h * 32 + ch] = f2bf(acc);
}

// ---------------------------------------------------------------- launch
extern "C" void kernel_launch(void* const* d_in, const int* in_sizes, int n_in,
                              void* d_out, int out_size, void* d_ws, size_t ws_size,
                              hipStream_t stream)
{
  const float* query = (const float*)d_in[0];
  const float* ctrl  = (const float*)d_in[1];
  const float* bev   = (const float*)d_in[2];
  // d_in[3] spatial_shapes int32 (=200,200) hardcoded
  const float* pc    = (const float*)d_in[4];
  const float* Wq    = (const float*)d_in[5];  const float* bq    = (const float*)d_in[6];
  const float* Wv    = (const float*)d_in[7];  const float* bv    = (const float*)d_in[8];
  const float* Woff  = (const float*)d_in[9];  const float* boff  = (const float*)d_in[10];
  const float* Wattn = (const float*)d_in[11]; const float* battn = (const float*)d_in[12];
  const float* Wmo   = (const float*)d_in[13]; const float* bmo   = (const float*)d_in[14];
  const float* Wo    = (const float*)d_in[15]; const float* bo    = (const float*)d_in[16];

  char* ws = (char*)d_ws;
  size_t off = 0;
  auto alloc = [&](size_t bytes) -> void* {
    void* p = ws + off; off += (bytes + 255) & ~(size_t)255; return p;
  };
  u16*  bevT = (u16*)alloc(4ull * 40000 * 256 * 2);    // 81.92 MB
  u16*  v    = (u16*)alloc(4ull * 8 * 40000 * 32 * 2); // 81.92 MB
  u16*  qin  = (u16*)alloc(3600ull * 256 * 2);
  u16*  wqT  = (u16*)alloc(65536 * 2);
  u16*  wvT  = (u16*)alloc(65536 * 2);
  u16*  woaT = (u16*)alloc(96 * 256 * 2);
  u16*  wmoT = (u16*)alloc(65536 * 2);
  u16*  woT  = (u16*)alloc(65536 * 2);
  float* boa = (float*)alloc(96 * 4);
  float* qf  = (float*)alloc(3600ull * 256 * 4);
  u16*  qb   = (u16*)alloc(3600ull * 256 * 2);
  float* oaf = (float*)alloc(3600ull * 96 * 4);
  u16*  atnO = (u16*)alloc(3600ull * 256 * 2);
  u16*  out1 = (u16*)alloc(3600ull * 256 * 2);
  (void)ws_size; (void)in_sizes; (void)n_in; (void)out_size;  // ~177 MB used

  prep_weights<<<256, 256, 0, stream>>>(Wq, Wv, Woff, Wattn, Wmo, Wo, boff, battn,
                                        wqT, wvT, woaT, wmoT, woT, boa);
  convert_q<<<900, 256, 0, stream>>>(query, qin);
  transpose_bev<<<dim3(625, 4, 4), 256, 0, stream>>>(bev, bevT);
  // q = query @ Wq + bq  -> bf16 + f32
  gemm_bt<GM_BOTH, false><<<dim3(2, 29, 1), 256, 0, stream>>>(
      qin, wqT, bq, nullptr, qb, qf, 3600, 256, 256, 0, 0);
  // [off|attn] = q @ [Woff|Wattn] + bias -> f32
  gemm_bt<GM_F32, false><<<dim3(1, 29, 1), 256, 0, stream>>>(
      qb, woaT, boa, nullptr, nullptr, oaf, 3600, 96, 256, 0, 0);
  // v^T = WvT . bevT  (per batch), store v[b][h][pix][32]
  gemm_bt<GM_V, false><<<dim3(313, 2, 4), 256, 0, stream>>>(
      wvT, bevT, bv, nullptr, v, nullptr, 256, 40000, 256,
      40000ll * 256, 8ll * 40000 * 32);
  sampler<<<7200, 256, 0, stream>>>(ctrl, pc, oaf, v, atnO);
  // out1 = attn_out @ Wmo + bmo + q
  gemm_bt<GM_BF16, true><<<dim3(2, 29, 1), 256, 0, stream>>>(
      atnO, wmoT, bmo, qf, out1, nullptr, 3600, 256, 256, 0, 0);
  // out2 = out1 @ Wo + bo -> d_out (f32)
  gemm_bt<GM_F32, false><<<dim3(2, 29, 1), 256, 0, stream>>>(
      out1, woT, bo, nullptr, nullptr, (float*)d_out, 3600, 256, 256, 0, 0);
}

// Round 4
// 432.900 us; speedup vs baseline: 1.0187x; 1.0187x over previous
//
#include <hip/hip_runtime.h>
#include <hip/hip_bf16.h>
#include <math.h>

// BezierDeformableAttention on MI355X (gfx950).
// Shapes: B=4 N=900 D=256 C=256 H=W=200, HEADS=8 PTS=4 K=10, hd=32.
// I/O dtype: float32. Internals: bf16 MFMA, f32 accumulate.
//
// R4 changes vs R3 (441 us):
//  - gemm_bt: global_load_lds width-16 staging (m97 ladder: 1.69x on this shape)
//  - transpose_bev: LDS stride 68 -> 66 (fixes 16-way phase-2 bank conflict -> 4-way)
//  - sampler: XCD-grouped block mapping (same (b,h) -> same blockIdx%8 -> L2 locality)
//  - convert_q merged into prep_weights (-1 dispatch)

typedef unsigned short u16;
typedef unsigned int u32;
typedef short bf16x8 __attribute__((ext_vector_type(8)));
typedef float f32x4 __attribute__((ext_vector_type(4)));

__device__ __forceinline__ float bf2f(u16 u) {
  union { u32 i; float f; } c; c.i = ((u32)u) << 16; return c.f;
}
__device__ __forceinline__ u16 f2bf(float f) {  // RNE
  union { float f; u32 i; } c; c.f = f;
  u32 u = c.i;
  return (u16)((u + 0x7FFFu + ((u >> 16) & 1u)) >> 16);
}
__device__ __forceinline__ int imin(int a, int b) { return a < b ? a : b; }
__device__ __forceinline__ int imax(int a, int b) { return a > b ? a : b; }

__device__ __forceinline__ void glds16(const u16* g, u16* l) {
  __builtin_amdgcn_global_load_lds(
      (__attribute__((address_space(1))) const void*)g,
      (__attribute__((address_space(3))) void*)l, 16, 0, 0);
}

// ------------------------------------------------ weights prep + q conversion
// grid 900 x 256 = 230400 threads.
__global__ __launch_bounds__(256) void prep_weights(
    const float* __restrict__ Wq, const float* __restrict__ Wv,
    const float* __restrict__ Woff, const float* __restrict__ Wattn,
    const float* __restrict__ Wmo, const float* __restrict__ Wo,
    const float* __restrict__ boff, const float* __restrict__ battn,
    const float* __restrict__ query,
    u16* __restrict__ wqT, u16* __restrict__ wvT, u16* __restrict__ woaT,
    u16* __restrict__ wmoT, u16* __restrict__ woT, float* __restrict__ boa,
    u16* __restrict__ qin)
{
  int idx = blockIdx.x * 256 + threadIdx.x;
  { // query f32 -> bf16, 921600 elems = 230400 threads x 4
    int i = idx * 4;
    float4 v = *(const float4*)(query + i);
    uint2 st;
    st.x = (u32)f2bf(v.x) | ((u32)f2bf(v.y) << 16);
    st.y = (u32)f2bf(v.z) | ((u32)f2bf(v.w) << 16);
    *(uint2*)(qin + i) = st;
  }
  if (idx < 65536) {
    int r = idx >> 8, c = idx & 255;  // out[r][c] = in[c][r]
    wqT[idx]  = f2bf(Wq[c * 256 + r]);
    wvT[idx]  = f2bf(Wv[c * 256 + r]);
    wmoT[idx] = f2bf(Wmo[c * 256 + r]);
    woT[idx]  = f2bf(Wo[c * 256 + r]);
  }
  if (idx < 96 * 256) {
    int n = idx >> 8, k = idx & 255;
    woaT[idx] = f2bf((n < 64) ? Woff[k * 64 + n] : Wattn[k * 32 + (n - 64)]);
  }
  if (idx < 96) boa[idx] = (idx < 64) ? boff[idx] : battn[idx - 64];
}

// ---------------------------------------------------------------- bev transpose
// (B,256,40000) f32 -> (B,40000,256) bf16. 64x64 tiles, LDS stride 66:
// phase1 u32 stores ~2-way; phase2 u16 reads banks = ci*8 + j + pr/2 -> 4-way.
__global__ __launch_bounds__(256) void transpose_bev(
    const float* __restrict__ bev, u16* __restrict__ bevT)
{
  __shared__ u16 t[64 * 66];
  const int b = blockIdx.z, c0 = blockIdx.y * 64, p0 = blockIdx.x * 64;
  const float* src = bev + ((size_t)b * 256 + c0) * 40000 + p0;
#pragma unroll
  for (int it = 0; it < 4; ++it) {
    int slot = it * 256 + threadIdx.x;        // 0..1023
    int r = slot >> 4, i = slot & 15;         // c-row r, pix-group i (4 f32)
    float4 dv = *(const float4*)(src + (size_t)r * 40000 + i * 4);
    u32* dst = (u32*)&t[r * 66 + i * 4];      // byte addr r*132+i*8: 4B aligned
    dst[0] = (u32)f2bf(dv.x) | ((u32)f2bf(dv.y) << 16);
    dst[1] = (u32)f2bf(dv.z) | ((u32)f2bf(dv.w) << 16);
  }
  __syncthreads();
  u16* ob = bevT + ((size_t)b * 40000 + p0) * 256 + c0;
#pragma unroll
  for (int it = 0; it < 2; ++it) {
    int slot = it * 256 + threadIdx.x;        // 0..511
    int pr = slot >> 3, ci = slot & 7;        // pix-row pr, c-group ci (8 bf16)
    u32 w0 = (u32)t[(ci * 8 + 0) * 66 + pr] | ((u32)t[(ci * 8 + 1) * 66 + pr] << 16);
    u32 w1 = (u32)t[(ci * 8 + 2) * 66 + pr] | ((u32)t[(ci * 8 + 3) * 66 + pr] << 16);
    u32 w2 = (u32)t[(ci * 8 + 4) * 66 + pr] | ((u32)t[(ci * 8 + 5) * 66 + pr] << 16);
    u32 w3 = (u32)t[(ci * 8 + 6) * 66 + pr] | ((u32)t[(ci * 8 + 7) * 66 + pr] << 16);
    uint4 ov; ov.x = w0; ov.y = w1; ov.z = w2; ov.w = w3;
    *(uint4*)(ob + (size_t)pr * 256 + ci * 8) = ov;
  }
}

// ---------------------------------------------------------------- MFMA GEMM
// C[M,N] = A[M,K] * Bt[N,K]^T (+bias f32)(+res f32). 128x128 tile, BK=32,
// 4 waves, each 64x64 = 4x4 MFMA 16x16x32. K multiple of 32 (256 here).
// Staging: global_load_lds dwordx4 (wave-uniform LDS base + lane*16B).
enum { GM_F32 = 0, GM_BF16 = 1, GM_BOTH = 2, GM_V = 3 };

template <int MODE, bool HAS_RES>
__global__ __launch_bounds__(256) void gemm_bt(
    const u16* __restrict__ A, const u16* __restrict__ Bt,
    const float* __restrict__ bias, const float* __restrict__ res,
    u16* __restrict__ outb, float* __restrict__ outf,
    int M, int N, int K, long long btStrideZ, long long outStrideZ)
{
  __shared__ __align__(16) u16 lA[128 * 32];
  __shared__ __align__(16) u16 lB[128 * 32];
  const int tid = threadIdx.x;
  const int wv = tid >> 6, lane = tid & 63;
  const int m0 = blockIdx.y * 128, n0 = blockIdx.x * 128;
  const u16* Bz = Bt + (size_t)blockIdx.z * btStrideZ;

  // wave wv stages chunks {wv, wv+4}; chunk = 16 rows x 32 k (1 KB);
  // lane's global row = chunkrow + (lane>>2), k-offset (lane&3)*8 -> lands at
  // LDS chunkbase + lane*16B == row-major [16][32].
  const int crow = lane >> 2;
  const int ckoff = (lane & 3) * 8;
  const int a1 = imin(m0 + wv * 16 + crow, M - 1);
  const int a2 = imin(m0 + (wv + 4) * 16 + crow, M - 1);
  const int b1 = imin(n0 + wv * 16 + crow, N - 1);
  const int b2 = imin(n0 + (wv + 4) * 16 + crow, N - 1);
  const u16* gA1 = A + (size_t)a1 * K + ckoff;
  const u16* gA2 = A + (size_t)a2 * K + ckoff;
  const u16* gB1 = Bz + (size_t)b1 * K + ckoff;
  const u16* gB2 = Bz + (size_t)b2 * K + ckoff;
  u16* lA1 = lA + wv * 512;  u16* lA2 = lA + (wv + 4) * 512;
  u16* lB1 = lB + wv * 512;  u16* lB2 = lB + (wv + 4) * 512;

  const int fm = (wv & 1) * 64, fn = (wv >> 1) * 64;
  const int fr = lane & 15, fk = (lane >> 4) * 8;

  f32x4 acc[4][4];
#pragma unroll
  for (int i = 0; i < 4; ++i)
#pragma unroll
    for (int j = 0; j < 4; ++j) acc[i][j] = (f32x4){0.f, 0.f, 0.f, 0.f};

  for (int k0 = 0; k0 < K; k0 += 32) {
    glds16(gA1 + k0, lA1);
    glds16(gA2 + k0, lA2);
    glds16(gB1 + k0, lB1);
    glds16(gB2 + k0, lB2);
    __syncthreads();  // drains vmcnt (DMA landed) + joins waves
    bf16x8 af[4], bfv[4];
#pragma unroll
    for (int i = 0; i < 4; ++i)
      af[i] = *(const bf16x8*)&lA[(fm + i * 16 + fr) * 32 + fk];
#pragma unroll
    for (int j = 0; j < 4; ++j)
      bfv[j] = *(const bf16x8*)&lB[(fn + j * 16 + fr) * 32 + fk];
    __syncthreads();  // all frag reads done before next iter's DMA overwrites
#pragma unroll
    for (int i = 0; i < 4; ++i)
#pragma unroll
      for (int j = 0; j < 4; ++j)
        acc[i][j] = __builtin_amdgcn_mfma_f32_16x16x32_bf16(af[i], bfv[j], acc[i][j], 0, 0, 0);
  }

  // epilogue: C/D layout col=lane&15, row=(lane>>4)*4+reg  [measured m89/m91]
  const int quad = lane >> 4;
#pragma unroll
  for (int j = 0; j < 4; ++j) {
    const int n = n0 + fn + j * 16 + fr;
    const bool nok = (n < N);
    float bcol = 0.f;
    if (MODE != GM_V) bcol = bias[nok ? n : 0];
#pragma unroll
    for (int i = 0; i < 4; ++i) {
      const int mb = m0 + fm + i * 16 + quad * 4;  // 4-aligned
      if (MODE == GM_V) {
        if (nok) {
          u16 u0 = f2bf(acc[i][j][0] + bias[mb + 0]);
          u16 u1 = f2bf(acc[i][j][1] + bias[mb + 1]);
          u16 u2 = f2bf(acc[i][j][2] + bias[mb + 2]);
          u16 u3 = f2bf(acc[i][j][3] + bias[mb + 3]);
          size_t off = (size_t)blockIdx.z * outStrideZ +
                       (size_t)(mb >> 5) * (40000 * 32) + (size_t)n * 32 + (mb & 31);
          uint2 st; st.x = (u32)u0 | ((u32)u1 << 16); st.y = (u32)u2 | ((u32)u3 << 16);
          *(uint2*)(outb + off) = st;
        }
      } else {
#pragma unroll
        for (int r = 0; r < 4; ++r) {
          const int m = mb + r;
          if (m < M && nok) {
            float x = acc[i][j][r] + bcol;
            if (HAS_RES) x += res[(size_t)m * N + n];
            if (MODE == GM_F32) outf[(size_t)m * N + n] = x;
            else if (MODE == GM_BF16) outb[(size_t)m * N + n] = f2bf(x);
            else { outb[(size_t)m * N + n] = f2bf(x); outf[(size_t)m * N + n] = x; }
          }
        }
      }
    }
  }
}

// ---------------------------------------------------------------- sampler
// One wave per (b,n,h). XCD-grouped: bh = blockIdx.x & 31 so all blocks of a
// given (b,h) land on XCD bh%8 (round-robin heuristic; perf only).
__global__ __launch_bounds__(256) void sampler(
    const float* __restrict__ ctrl,  // (3600,4,2) f32
    const float* __restrict__ pc,    // (6,) f32
    const float* __restrict__ oa_,   // (3600,96) f32: [0:64) off, [64:96) attn
    const u16* __restrict__ v,       // (B,8,40000,32) bf16
    u16* __restrict__ attn_out)      // (3600,256) bf16
{
  __shared__ int   sX0[4][40], sY0[4][40];
  __shared__ float sWx[4][40], sWy[4][40], sAw[4][40];
  const int w = threadIdx.x >> 6, lane = threadIdx.x & 63;
  const int bh = blockIdx.x & 31;          // (b*8+h)
  const int n = (blockIdx.x >> 5) * 4 + w; // 225*4 = 900
  const int h = bh & 7, b = bh >> 3;
  const int row = b * 900 + n;

  if (lane < 40) {
    const int k = lane >> 2, p = lane & 3;
    const float t = (float)k * (1.0f / 9.0f), u = 1.f - t;
    const float c0 = u * u * u, c1 = 3.f * u * u * t, c2 = 3.f * u * t * t, c3 = t * t * t;
    const float* cp = ctrl + (size_t)row * 8;
    float cx = c0 * cp[0] + c1 * cp[2] + c2 * cp[4] + c3 * cp[6];
    float cy = c0 * cp[1] + c1 * cp[3] + c2 * cp[5] + c3 * cp[7];
    float nx = (cx - pc[0]) / (pc[3] - pc[0]);
    float ny = (cy - pc[1]) / (pc[4] - pc[1]);
    nx = fminf(fmaxf(nx, 0.01f), 0.99f);
    ny = fminf(fmaxf(ny, 0.01f), 0.99f);
    const float* oa = oa_ + (size_t)row * 96;
    float ox = oa[h * 8 + p * 2 + 0], oy = oa[h * 8 + p * 2 + 1];
    float l0 = oa[64 + h * 4 + 0], l1 = oa[64 + h * 4 + 1];
    float l2 = oa[64 + h * 4 + 2], l3 = oa[64 + h * 4 + 3];
    float mx = fmaxf(fmaxf(l0, l1), fmaxf(l2, l3));
    float e0 = __expf(l0 - mx), e1 = __expf(l1 - mx), e2 = __expf(l2 - mx), e3 = __expf(l3 - mx);
    float lp = (p == 0) ? l0 : (p == 1) ? l1 : (p == 2) ? l2 : l3;
    float aw = __expf(lp - mx) / (e0 + e1 + e2 + e3);
    float gx = (nx + ox * (1.f / 200.f)) * 200.f - 0.5f;
    float gy = (ny + oy * (1.f / 200.f)) * 200.f - 0.5f;
    float x0 = floorf(gx), y0 = floorf(gy);
    sX0[w][lane] = (int)x0; sY0[w][lane] = (int)y0;
    sWx[w][lane] = gx - x0; sWy[w][lane] = gy - y0; sAw[w][lane] = aw;
  }
  __syncthreads();

  const int sub = lane >> 5, ch = lane & 31;
  const u16* vb = v + ((size_t)(b * 8 + h)) * (40000 * 32) + ch;
  float acc = 0.f;
#pragma unroll 4
  for (int i = 0; i < 20; ++i) {
    const int s = sub * 20 + i;
    const int x0 = sX0[w][s], y0 = sY0[w][s];
    const float wx = sWx[w][s], wy = sWy[w][s], aw = sAw[w][s];
    const int x1 = x0 + 1, y1 = y0 + 1;
    const int cx0 = imin(imax(x0, 0), 199), cx1 = imin(imax(x1, 0), 199);
    const int cy0 = imin(imax(y0, 0), 199), cy1 = imin(imax(y1, 0), 199);
    const bool vx0 = (u32)x0 < 200u, vx1 = (u32)x1 < 200u;
    const bool vy0 = (u32)y0 < 200u, vy1 = (u32)y1 < 200u;
    const u16* r0 = vb + (size_t)(cy0 * 200) * 32;
    const u16* r1 = vb + (size_t)(cy1 * 200) * 32;
    float f00 = bf2f(r0[cx0 * 32]);
    float f10 = bf2f(r0[cx1 * 32]);
    float f01 = bf2f(r1[cx0 * 32]);
    float f11 = bf2f(r1[cx1 * 32]);
    float w00 = (vx0 && vy0) ? (1.f - wx) * (1.f - wy) : 0.f;
    float w10 = (vx1 && vy0) ? wx * (1.f - wy) : 0.f;
    float w01 = (vx0 && vy1) ? (1.f - wx) * wy : 0.f;
    float w11 = (vx1 && vy1) ? wx * wy : 0.f;
    acc += aw * (w00 * f00 + w10 * f10 + w01 * f01 + w11 * f11);
  }
  acc += __shfl_down(acc, 32);
  if (lane < 32) attn_out[(size_t)row * 256 + h * 32 + ch] = f2bf(acc);
}

// ---------------------------------------------------------------- launch
extern "C" void kernel_launch(void* const* d_in, const int* in_sizes, int n_in,
                              void* d_out, int out_size, void* d_ws, size_t ws_size,
                              hipStream_t stream)
{
  const float* query = (const float*)d_in[0];
  const float* ctrl  = (const float*)d_in[1];
  const float* bev   = (const float*)d_in[2];
  // d_in[3] spatial_shapes int32 (=200,200) hardcoded
  const float* pc    = (const float*)d_in[4];
  const float* Wq    = (const float*)d_in[5];  const float* bq    = (const float*)d_in[6];
  const float* Wv    = (const float*)d_in[7];  const float* bv    = (const float*)d_in[8];
  const float* Woff  = (const float*)d_in[9];  const float* boff  = (const float*)d_in[10];
  const float* Wattn = (const float*)d_in[11]; const float* battn = (const float*)d_in[12];
  const float* Wmo   = (const float*)d_in[13]; const float* bmo   = (const float*)d_in[14];
  const float* Wo    = (const float*)d_in[15]; const float* bo    = (const float*)d_in[16];

  char* ws = (char*)d_ws;
  size_t off = 0;
  auto alloc = [&](size_t bytes) -> void* {
    void* p = ws + off; off += (bytes + 255) & ~(size_t)255; return p;
  };
  u16*  bevT = (u16*)alloc(4ull * 40000 * 256 * 2);    // 81.92 MB
  u16*  v    = (u16*)alloc(4ull * 8 * 40000 * 32 * 2); // 81.92 MB
  u16*  qin  = (u16*)alloc(3600ull * 256 * 2);
  u16*  wqT  = (u16*)alloc(65536 * 2);
  u16*  wvT  = (u16*)alloc(65536 * 2);
  u16*  woaT = (u16*)alloc(96 * 256 * 2);
  u16*  wmoT = (u16*)alloc(65536 * 2);
  u16*  woT  = (u16*)alloc(65536 * 2);
  float* boa = (float*)alloc(96 * 4);
  float* qf  = (float*)alloc(3600ull * 256 * 4);
  u16*  qb   = (u16*)alloc(3600ull * 256 * 2);
  float* oaf = (float*)alloc(3600ull * 96 * 4);
  u16*  atnO = (u16*)alloc(3600ull * 256 * 2);
  u16*  out1 = (u16*)alloc(3600ull * 256 * 2);
  (void)ws_size; (void)in_sizes; (void)n_in; (void)out_size;  // ~177 MB used

  prep_weights<<<900, 256, 0, stream>>>(Wq, Wv, Woff, Wattn, Wmo, Wo, boff, battn,
                                        query, wqT, wvT, woaT, wmoT, woT, boa, qin);
  transpose_bev<<<dim3(625, 4, 4), 256, 0, stream>>>(bev, bevT);
  // q = query @ Wq + bq  -> bf16 + f32
  gemm_bt<GM_BOTH, false><<<dim3(2, 29, 1), 256, 0, stream>>>(
      qin, wqT, bq, nullptr, qb, qf, 3600, 256, 256, 0, 0);
  // [off|attn] = q @ [Woff|Wattn] + bias -> f32
  gemm_bt<GM_F32, false><<<dim3(1, 29, 1), 256, 0, stream>>>(
      qb, woaT, boa, nullptr, nullptr, oaf, 3600, 96, 256, 0, 0);
  // v^T = WvT . bevT  (per batch), store v[b][h][pix][32]
  gemm_bt<GM_V, false><<<dim3(313, 2, 4), 256, 0, stream>>>(
      wvT, bevT, bv, nullptr, v, nullptr, 256, 40000, 256,
      40000ll * 256, 8ll * 40000 * 32);
  sampler<<<7200, 256, 0, stream>>>(ctrl, pc, oaf, v, atnO);
  // out1 = attn_out @ Wmo + bmo + q
  gemm_bt<GM_BF16, true><<<dim3(2, 29, 1), 256, 0, stream>>>(
      atnO, wmoT, bmo, qf, out1, nullptr, 3600, 256, 256, 0, 0);
  // out2 = out1 @ Wo + bo -> d_out (f32)
  gemm_bt<GM_F32, false><<<dim3(2, 29, 1), 256, 0, stream>>>(
      out1, woT, bo, nullptr, nullptr, (float*)d_out, 3600, 256, 256, 0, 0);
}

// Round 5
// 419.268 us; speedup vs baseline: 1.0518x; 1.0325x over previous
//
#include <hip/hip_runtime.h>
#include <hip/hip_bf16.h>
#include <math.h>

// BezierDeformableAttention on MI355X (gfx950).
// Shapes: B=4 N=900 D=256 C=256 H=W=200, HEADS=8 PTS=4 K=10, hd=32.
// I/O dtype: float32. Internals: bf16 MFMA, f32 accumulate.
//
// R5 changes vs R4 (433 us):
//  - sampler: 4 channels/lane via uint2 loads (20 dwordx2 vs 80 ushort loads
//    per wave), shared address math, shfl_xor reduction over sample groups.
//  - v-GEMM: grid (2,313,4) with x=m-tile so both m-passes over a B-tile are
//    temporally adjacent (L3 reuse).

typedef unsigned short u16;
typedef unsigned int u32;
typedef short bf16x8 __attribute__((ext_vector_type(8)));
typedef float f32x4 __attribute__((ext_vector_type(4)));

__device__ __forceinline__ float bf2f(u16 u) {
  union { u32 i; float f; } c; c.i = ((u32)u) << 16; return c.f;
}
__device__ __forceinline__ float bflo(u32 w) {  // low bf16 of packed word
  union { u32 i; float f; } c; c.i = w << 16; return c.f;
}
__device__ __forceinline__ float bfhi(u32 w) {  // high bf16 of packed word
  union { u32 i; float f; } c; c.i = w & 0xffff0000u; return c.f;
}
__device__ __forceinline__ u16 f2bf(float f) {  // RNE
  union { float f; u32 i; } c; c.f = f;
  u32 u = c.i;
  return (u16)((u + 0x7FFFu + ((u >> 16) & 1u)) >> 16);
}
__device__ __forceinline__ int imin(int a, int b) { return a < b ? a : b; }
__device__ __forceinline__ int imax(int a, int b) { return a > b ? a : b; }

__device__ __forceinline__ void glds16(const u16* g, u16* l) {
  __builtin_amdgcn_global_load_lds(
      (__attribute__((address_space(1))) const void*)g,
      (__attribute__((address_space(3))) void*)l, 16, 0, 0);
}

// ------------------------------------------------ weights prep + q conversion
__global__ __launch_bounds__(256) void prep_weights(
    const float* __restrict__ Wq, const float* __restrict__ Wv,
    const float* __restrict__ Woff, const float* __restrict__ Wattn,
    const float* __restrict__ Wmo, const float* __restrict__ Wo,
    const float* __restrict__ boff, const float* __restrict__ battn,
    const float* __restrict__ query,
    u16* __restrict__ wqT, u16* __restrict__ wvT, u16* __restrict__ woaT,
    u16* __restrict__ wmoT, u16* __restrict__ woT, float* __restrict__ boa,
    u16* __restrict__ qin)
{
  int idx = blockIdx.x * 256 + threadIdx.x;
  { // query f32 -> bf16, 921600 elems = 230400 threads x 4
    int i = idx * 4;
    float4 v = *(const float4*)(query + i);
    uint2 st;
    st.x = (u32)f2bf(v.x) | ((u32)f2bf(v.y) << 16);
    st.y = (u32)f2bf(v.z) | ((u32)f2bf(v.w) << 16);
    *(uint2*)(qin + i) = st;
  }
  if (idx < 65536) {
    int r = idx >> 8, c = idx & 255;  // out[r][c] = in[c][r]
    wqT[idx]  = f2bf(Wq[c * 256 + r]);
    wvT[idx]  = f2bf(Wv[c * 256 + r]);
    wmoT[idx] = f2bf(Wmo[c * 256 + r]);
    woT[idx]  = f2bf(Wo[c * 256 + r]);
  }
  if (idx < 96 * 256) {
    int n = idx >> 8, k = idx & 255;
    woaT[idx] = f2bf((n < 64) ? Woff[k * 64 + n] : Wattn[k * 32 + (n - 64)]);
  }
  if (idx < 96) boa[idx] = (idx < 64) ? boff[idx] : battn[idx - 64];
}

// ---------------------------------------------------------------- bev transpose
// (B,256,40000) f32 -> (B,40000,256) bf16. 64x64 tiles, LDS stride 66.
__global__ __launch_bounds__(256) void transpose_bev(
    const float* __restrict__ bev, u16* __restrict__ bevT)
{
  __shared__ u16 t[64 * 66];
  const int b = blockIdx.z, c0 = blockIdx.y * 64, p0 = blockIdx.x * 64;
  const float* src = bev + ((size_t)b * 256 + c0) * 40000 + p0;
#pragma unroll
  for (int it = 0; it < 4; ++it) {
    int slot = it * 256 + threadIdx.x;        // 0..1023
    int r = slot >> 4, i = slot & 15;         // c-row r, pix-group i (4 f32)
    float4 dv = *(const float4*)(src + (size_t)r * 40000 + i * 4);
    u32* dst = (u32*)&t[r * 66 + i * 4];
    dst[0] = (u32)f2bf(dv.x) | ((u32)f2bf(dv.y) << 16);
    dst[1] = (u32)f2bf(dv.z) | ((u32)f2bf(dv.w) << 16);
  }
  __syncthreads();
  u16* ob = bevT + ((size_t)b * 40000 + p0) * 256 + c0;
#pragma unroll
  for (int it = 0; it < 2; ++it) {
    int slot = it * 256 + threadIdx.x;        // 0..511
    int pr = slot >> 3, ci = slot & 7;        // pix-row pr, c-group ci (8 bf16)
    u32 w0 = (u32)t[(ci * 8 + 0) * 66 + pr] | ((u32)t[(ci * 8 + 1) * 66 + pr] << 16);
    u32 w1 = (u32)t[(ci * 8 + 2) * 66 + pr] | ((u32)t[(ci * 8 + 3) * 66 + pr] << 16);
    u32 w2 = (u32)t[(ci * 8 + 4) * 66 + pr] | ((u32)t[(ci * 8 + 5) * 66 + pr] << 16);
    u32 w3 = (u32)t[(ci * 8 + 6) * 66 + pr] | ((u32)t[(ci * 8 + 7) * 66 + pr] << 16);
    uint4 ov; ov.x = w0; ov.y = w1; ov.z = w2; ov.w = w3;
    *(uint4*)(ob + (size_t)pr * 256 + ci * 8) = ov;
  }
}

// ---------------------------------------------------------------- MFMA GEMM
enum { GM_F32 = 0, GM_BF16 = 1, GM_BOTH = 2, GM_V = 3 };

template <int MODE, bool HAS_RES, bool XY_SWAP>
__global__ __launch_bounds__(256) void gemm_bt(
    const u16* __restrict__ A, const u16* __restrict__ Bt,
    const float* __restrict__ bias, const float* __restrict__ res,
    u16* __restrict__ outb, float* __restrict__ outf,
    int M, int N, int K, long long btStrideZ, long long outStrideZ)
{
  __shared__ __align__(16) u16 lA[128 * 32];
  __shared__ __align__(16) u16 lB[128 * 32];
  const int tid = threadIdx.x;
  const int wv = tid >> 6, lane = tid & 63;
  const int m0 = (XY_SWAP ? blockIdx.x : blockIdx.y) * 128;
  const int n0 = (XY_SWAP ? blockIdx.y : blockIdx.x) * 128;
  const u16* Bz = Bt + (size_t)blockIdx.z * btStrideZ;

  const int crow = lane >> 2;
  const int ckoff = (lane & 3) * 8;
  const int a1 = imin(m0 + wv * 16 + crow, M - 1);
  const int a2 = imin(m0 + (wv + 4) * 16 + crow, M - 1);
  const int b1 = imin(n0 + wv * 16 + crow, N - 1);
  const int b2 = imin(n0 + (wv + 4) * 16 + crow, N - 1);
  const u16* gA1 = A + (size_t)a1 * K + ckoff;
  const u16* gA2 = A + (size_t)a2 * K + ckoff;
  const u16* gB1 = Bz + (size_t)b1 * K + ckoff;
  const u16* gB2 = Bz + (size_t)b2 * K + ckoff;
  u16* lA1 = lA + wv * 512;  u16* lA2 = lA + (wv + 4) * 512;
  u16* lB1 = lB + wv * 512;  u16* lB2 = lB + (wv + 4) * 512;

  const int fm = (wv & 1) * 64, fn = (wv >> 1) * 64;
  const int fr = lane & 15, fk = (lane >> 4) * 8;

  f32x4 acc[4][4];
#pragma unroll
  for (int i = 0; i < 4; ++i)
#pragma unroll
    for (int j = 0; j < 4; ++j) acc[i][j] = (f32x4){0.f, 0.f, 0.f, 0.f};

  for (int k0 = 0; k0 < K; k0 += 32) {
    glds16(gA1 + k0, lA1);
    glds16(gA2 + k0, lA2);
    glds16(gB1 + k0, lB1);
    glds16(gB2 + k0, lB2);
    __syncthreads();
    bf16x8 af[4], bfv[4];
#pragma unroll
    for (int i = 0; i < 4; ++i)
      af[i] = *(const bf16x8*)&lA[(fm + i * 16 + fr) * 32 + fk];
#pragma unroll
    for (int j = 0; j < 4; ++j)
      bfv[j] = *(const bf16x8*)&lB[(fn + j * 16 + fr) * 32 + fk];
    __syncthreads();
#pragma unroll
    for (int i = 0; i < 4; ++i)
#pragma unroll
      for (int j = 0; j < 4; ++j)
        acc[i][j] = __builtin_amdgcn_mfma_f32_16x16x32_bf16(af[i], bfv[j], acc[i][j], 0, 0, 0);
  }

  // epilogue: C/D layout col=lane&15, row=(lane>>4)*4+reg  [measured m89/m91]
  const int quad = lane >> 4;
#pragma unroll
  for (int j = 0; j < 4; ++j) {
    const int n = n0 + fn + j * 16 + fr;
    const bool nok = (n < N);
    float bcol = 0.f;
    if (MODE != GM_V) bcol = bias[nok ? n : 0];
#pragma unroll
    for (int i = 0; i < 4; ++i) {
      const int mb = m0 + fm + i * 16 + quad * 4;
      if (MODE == GM_V) {
        if (nok) {
          u16 u0 = f2bf(acc[i][j][0] + bias[mb + 0]);
          u16 u1 = f2bf(acc[i][j][1] + bias[mb + 1]);
          u16 u2 = f2bf(acc[i][j][2] + bias[mb + 2]);
          u16 u3 = f2bf(acc[i][j][3] + bias[mb + 3]);
          size_t off = (size_t)blockIdx.z * outStrideZ +
                       (size_t)(mb >> 5) * (40000 * 32) + (size_t)n * 32 + (mb & 31);
          uint2 st; st.x = (u32)u0 | ((u32)u1 << 16); st.y = (u32)u2 | ((u32)u3 << 16);
          *(uint2*)(outb + off) = st;
        }
      } else {
#pragma unroll
        for (int r = 0; r < 4; ++r) {
          const int m = mb + r;
          if (m < M && nok) {
            float x = acc[i][j][r] + bcol;
            if (HAS_RES) x += res[(size_t)m * N + n];
            if (MODE == GM_F32) outf[(size_t)m * N + n] = x;
            else if (MODE == GM_BF16) outb[(size_t)m * N + n] = f2bf(x);
            else { outb[(size_t)m * N + n] = f2bf(x); outf[(size_t)m * N + n] = x; }
          }
        }
      }
    }
  }
}

// ---------------------------------------------------------------- sampler
// One wave per (b,n,h). Lane = (sample-group s = lane>>3) x (chgrp = lane&7).
// Each lane: 4 channels (uint2 = 8B) per corner; 5 passes x 8 samples = 40.
// Cross-lane shfl_xor reduce over the 8 sample-groups at the end.
__global__ __launch_bounds__(256) void sampler(
    const float* __restrict__ ctrl,  // (3600,4,2) f32
    const float* __restrict__ pc,    // (6,) f32
    const float* __restrict__ oa_,   // (3600,96) f32: [0:64) off, [64:96) attn
    const u16* __restrict__ v,       // (B,8,40000,32) bf16
    u16* __restrict__ attn_out)      // (3600,256) bf16
{
  __shared__ int   sX0[4][40], sY0[4][40];
  __shared__ float sWx[4][40], sWy[4][40], sAw[4][40];
  const int w = threadIdx.x >> 6, lane = threadIdx.x & 63;
  const int bh = blockIdx.x & 31;          // (b*8+h)
  const int n = (blockIdx.x >> 5) * 4 + w; // 225*4 = 900
  const int h = bh & 7, b = bh >> 3;
  const int row = b * 900 + n;

  if (lane < 40) {
    const int k = lane >> 2, p = lane & 3;
    const float t = (float)k * (1.0f / 9.0f), u = 1.f - t;
    const float c0 = u * u * u, c1 = 3.f * u * u * t, c2 = 3.f * u * t * t, c3 = t * t * t;
    const float* cp = ctrl + (size_t)row * 8;
    float cx = c0 * cp[0] + c1 * cp[2] + c2 * cp[4] + c3 * cp[6];
    float cy = c0 * cp[1] + c1 * cp[3] + c2 * cp[5] + c3 * cp[7];
    float nx = (cx - pc[0]) / (pc[3] - pc[0]);
    float ny = (cy - pc[1]) / (pc[4] - pc[1]);
    nx = fminf(fmaxf(nx, 0.01f), 0.99f);
    ny = fminf(fmaxf(ny, 0.01f), 0.99f);
    const float* oa = oa_ + (size_t)row * 96;
    float ox = oa[h * 8 + p * 2 + 0], oy = oa[h * 8 + p * 2 + 1];
    float l0 = oa[64 + h * 4 + 0], l1 = oa[64 + h * 4 + 1];
    float l2 = oa[64 + h * 4 + 2], l3 = oa[64 + h * 4 + 3];
    float mx = fmaxf(fmaxf(l0, l1), fmaxf(l2, l3));
    float e0 = __expf(l0 - mx), e1 = __expf(l1 - mx), e2 = __expf(l2 - mx), e3 = __expf(l3 - mx);
    float lp = (p == 0) ? l0 : (p == 1) ? l1 : (p == 2) ? l2 : l3;
    float aw = __expf(lp - mx) / (e0 + e1 + e2 + e3);
    float gx = (nx + ox * (1.f / 200.f)) * 200.f - 0.5f;
    float gy = (ny + oy * (1.f / 200.f)) * 200.f - 0.5f;
    float x0 = floorf(gx), y0 = floorf(gy);
    sX0[w][lane] = (int)x0; sY0[w][lane] = (int)y0;
    sWx[w][lane] = gx - x0; sWy[w][lane] = gy - y0; sAw[w][lane] = aw;
  }
  __syncthreads();

  const int sg = lane >> 3;        // sample group 0..7
  const int ch0 = (lane & 7) * 4;  // 4 channels
  const u16* vb = v + ((size_t)(b * 8 + h)) * (40000 * 32) + ch0;
  float a0 = 0.f, a1 = 0.f, a2 = 0.f, a3 = 0.f;
#pragma unroll
  for (int p = 0; p < 5; ++p) {
    const int s = p * 8 + sg;
    const int x0 = sX0[w][s], y0 = sY0[w][s];
    const float wx = sWx[w][s], wy = sWy[w][s], aw = sAw[w][s];
    const int x1 = x0 + 1, y1 = y0 + 1;
    const int cx0 = imin(imax(x0, 0), 199), cx1 = imin(imax(x1, 0), 199);
    const int cy0 = imin(imax(y0, 0), 199), cy1 = imin(imax(y1, 0), 199);
    const bool vx0 = (u32)x0 < 200u, vx1 = (u32)x1 < 200u;
    const bool vy0 = (u32)y0 < 200u, vy1 = (u32)y1 < 200u;
    const float w00 = (vx0 && vy0) ? aw * (1.f - wx) * (1.f - wy) : 0.f;
    const float w10 = (vx1 && vy0) ? aw * wx * (1.f - wy) : 0.f;
    const float w01 = (vx0 && vy1) ? aw * (1.f - wx) * wy : 0.f;
    const float w11 = (vx1 && vy1) ? aw * wx * wy : 0.f;
    uint2 d00 = *(const uint2*)(vb + (size_t)(cy0 * 200 + cx0) * 32);
    uint2 d10 = *(const uint2*)(vb + (size_t)(cy0 * 200 + cx1) * 32);
    uint2 d01 = *(const uint2*)(vb + (size_t)(cy1 * 200 + cx0) * 32);
    uint2 d11 = *(const uint2*)(vb + (size_t)(cy1 * 200 + cx1) * 32);
    a0 += w00 * bflo(d00.x) + w10 * bflo(d10.x) + w01 * bflo(d01.x) + w11 * bflo(d11.x);
    a1 += w00 * bfhi(d00.x) + w10 * bfhi(d10.x) + w01 * bfhi(d01.x) + w11 * bfhi(d11.x);
    a2 += w00 * bflo(d00.y) + w10 * bflo(d10.y) + w01 * bflo(d01.y) + w11 * bflo(d11.y);
    a3 += w00 * bfhi(d00.y) + w10 * bfhi(d10.y) + w01 * bfhi(d01.y) + w11 * bfhi(d11.y);
  }
#pragma unroll
  for (int off = 8; off < 64; off <<= 1) {
    a0 += __shfl_xor(a0, off);
    a1 += __shfl_xor(a1, off);
    a2 += __shfl_xor(a2, off);
    a3 += __shfl_xor(a3, off);
  }
  if (lane < 8) {
    uint2 st;
    st.x = (u32)f2bf(a0) | ((u32)f2bf(a1) << 16);
    st.y = (u32)f2bf(a2) | ((u32)f2bf(a3) << 16);
    *(uint2*)(attn_out + (size_t)row * 256 + h * 32 + ch0) = st;
  }
}

// ---------------------------------------------------------------- launch
extern "C" void kernel_launch(void* const* d_in, const int* in_sizes, int n_in,
                              void* d_out, int out_size, void* d_ws, size_t ws_size,
                              hipStream_t stream)
{
  const float* query = (const float*)d_in[0];
  const float* ctrl  = (const float*)d_in[1];
  const float* bev   = (const float*)d_in[2];
  // d_in[3] spatial_shapes int32 (=200,200) hardcoded
  const float* pc    = (const float*)d_in[4];
  const float* Wq    = (const float*)d_in[5];  const float* bq    = (const float*)d_in[6];
  const float* Wv    = (const float*)d_in[7];  const float* bv    = (const float*)d_in[8];
  const float* Woff  = (const float*)d_in[9];  const float* boff  = (const float*)d_in[10];
  const float* Wattn = (const float*)d_in[11]; const float* battn = (const float*)d_in[12];
  const float* Wmo   = (const float*)d_in[13]; const float* bmo   = (const float*)d_in[14];
  const float* Wo    = (const float*)d_in[15]; const float* bo    = (const float*)d_in[16];

  char* ws = (char*)d_ws;
  size_t off = 0;
  auto alloc = [&](size_t bytes) -> void* {
    void* p = ws + off; off += (bytes + 255) & ~(size_t)255; return p;
  };
  u16*  bevT = (u16*)alloc(4ull * 40000 * 256 * 2);    // 81.92 MB
  u16*  v    = (u16*)alloc(4ull * 8 * 40000 * 32 * 2); // 81.92 MB
  u16*  qin  = (u16*)alloc(3600ull * 256 * 2);
  u16*  wqT  = (u16*)alloc(65536 * 2);
  u16*  wvT  = (u16*)alloc(65536 * 2);
  u16*  woaT = (u16*)alloc(96 * 256 * 2);
  u16*  wmoT = (u16*)alloc(65536 * 2);
  u16*  woT  = (u16*)alloc(65536 * 2);
  float* boa = (float*)alloc(96 * 4);
  float* qf  = (float*)alloc(3600ull * 256 * 4);
  u16*  qb   = (u16*)alloc(3600ull * 256 * 2);
  float* oaf = (float*)alloc(3600ull * 96 * 4);
  u16*  atnO = (u16*)alloc(3600ull * 256 * 2);
  u16*  out1 = (u16*)alloc(3600ull * 256 * 2);
  (void)ws_size; (void)in_sizes; (void)n_in; (void)out_size;

  prep_weights<<<900, 256, 0, stream>>>(Wq, Wv, Woff, Wattn, Wmo, Wo, boff, battn,
                                        query, wqT, wvT, woaT, wmoT, woT, boa, qin);
  transpose_bev<<<dim3(625, 4, 4), 256, 0, stream>>>(bev, bevT);
  gemm_bt<GM_BOTH, false, false><<<dim3(2, 29, 1), 256, 0, stream>>>(
      qin, wqT, bq, nullptr, qb, qf, 3600, 256, 256, 0, 0);
  gemm_bt<GM_F32, false, false><<<dim3(1, 29, 1), 256, 0, stream>>>(
      qb, woaT, boa, nullptr, nullptr, oaf, 3600, 96, 256, 0, 0);
  gemm_bt<GM_V, false, true><<<dim3(2, 313, 4), 256, 0, stream>>>(
      wvT, bevT, bv, nullptr, v, nullptr, 256, 40000, 256,
      40000ll * 256, 8ll * 40000 * 32);
  sampler<<<7200, 256, 0, stream>>>(ctrl, pc, oaf, v, atnO);
  gemm_bt<GM_BF16, true, false><<<dim3(2, 29, 1), 256, 0, stream>>>(
      atnO, wmoT, bmo, qf, out1, nullptr, 3600, 256, 256, 0, 0);
  gemm_bt<GM_F32, false, false><<<dim3(2, 29, 1), 256, 0, stream>>>(
      out1, woT, bo, nullptr, nullptr, (float*)d_out, 3600, 256, 256, 0, 0);
}